// Round 1
// baseline (1798.587 us; speedup 1.0000x reference)
//
#include <hip/hip_runtime.h>

// Problem constants (fixed by the reference)
constexpr int N_ATOMS = 50000;
constexpr int N_EDGES = 800000;
constexpr int ELEM    = 64;
constexpr int D_IN    = 192;   // 2*ELEM + NBR
constexpr int D_OUT   = 128;   // 2*ELEM
constexpr float EPS   = 1e-5f;

constexpr int TILE_M = 64;     // edges per GEMM block

// Workspace layout (bytes)
constexpr size_t OFF_T   = 0;                                      // bf16 T[E][128]
constexpr size_t OFF_NS  = OFF_T  + (size_t)N_EDGES * D_OUT * 2;   // f32 nbr_sumed[N][64]
constexpr size_t OFF_BN1 = OFF_NS + (size_t)N_ATOMS * ELEM * 4;    // f32 [256] sum/sumsq
constexpr size_t OFF_SC1 = OFF_BN1 + 256 * 4;                      // f32 [256] scale/shift
constexpr size_t OFF_BN2 = OFF_SC1 + 256 * 4;                      // f32 [128] sum/sumsq
constexpr size_t OFF_RS  = OFF_BN2 + 128 * 4;                      // int [N] row_start
constexpr size_t OFF_RE  = OFF_RS + (size_t)N_ATOMS * 4;           // int [N] row_end
// total ~218 MB

// ---- bf16 helpers (manual, avoids __hip_bfloat16 union/ctor issues) ----
__device__ __forceinline__ unsigned short f32_to_bf16(float f) {
    unsigned int u = __float_as_uint(f);
    u = (u + 0x7fffu + ((u >> 16) & 1u)) >> 16;   // RNE
    return (unsigned short)u;
}
__device__ __forceinline__ float bf16_to_f32(unsigned short h) {
    return __uint_as_float(((unsigned int)h) << 16);
}
__device__ __forceinline__ float softplus_f(float x) {
    return fmaxf(x, 0.f) + log1pf(__expf(-fabsf(x)));
}

// ---- 0: init accumulators / segment bounds ----
__global__ void init_kernel(int* __restrict__ rs, int* __restrict__ re,
                            float* __restrict__ bn1, float* __restrict__ bn2) {
    int i = blockIdx.x * blockDim.x + threadIdx.x;
    if (i < N_ATOMS) { rs[i] = N_EDGES; re[i] = 0; }
    if (i < 256) bn1[i] = 0.f;
    if (i < 128) bn2[i] = 0.f;
}

// ---- 1: per-atom edge ranges (self_fea_idx is sorted) ----
__global__ void bounds_kernel(const int* __restrict__ sidx,
                              int* __restrict__ rs, int* __restrict__ re) {
    int e = blockIdx.x * blockDim.x + threadIdx.x;
    if (e < N_EDGES) {
        int s = sidx[e];
        atomicMin(&rs[s], e);
        atomicMax(&re[s], e + 1);
    }
}

// ---- 2: fused gather + GEMM (fp32), store T (bf16) + BN1 partial stats ----
// Block: 256 threads. Tile: 64 edges x 128 cols, K staged in chunks of 64
// (chunk 0 = atom[self], chunk 1 = atom[nbr], chunk 2 = nbr_fea).
__global__ __launch_bounds__(256) void gemm_kernel(
    const float* __restrict__ atom, const float* __restrict__ nbrf,
    const int* __restrict__ sidx, const int* __restrict__ nidx,
    const float* __restrict__ W, const float* __restrict__ bias,
    unsigned short* __restrict__ T, float* __restrict__ bn1_stats)
{
    __shared__ float As[TILE_M][64];    // 16 KB
    __shared__ float Bs[64][D_OUT];     // 32 KB
    __shared__ float stats_s[256];      // 1 KB

    const int tid = threadIdx.x;
    const int e0  = blockIdx.x * TILE_M;
    const int tx  = tid & 31;           // 32 col-groups of 4 -> 128 cols
    const int ty  = tid >> 5;           // 8 row-groups of 8 -> 64 rows

    stats_s[tid] = 0.f;

    float acc[8][4];
    #pragma unroll
    for (int r = 0; r < 8; ++r)
        #pragma unroll
        for (int j = 0; j < 4; ++j) acc[r][j] = 0.f;

    for (int chunk = 0; chunk < 3; ++chunk) {
        // stage A tile: 64 rows x 64 f32 (1024 float4, 4 per thread)
        #pragma unroll
        for (int i = 0; i < 4; ++i) {
            int flat = tid + 256 * i;
            int r = flat >> 4;
            int q = flat & 15;
            int e = e0 + r;
            const float* src;
            if (chunk == 0)      src = atom + (size_t)sidx[e] * 64;
            else if (chunk == 1) src = atom + (size_t)nidx[e] * 64;
            else                 src = nbrf + (size_t)e * 64;
            *(float4*)&As[r][q * 4] = *(const float4*)(src + q * 4);
        }
        // stage W chunk: 64 x 128 f32 (2048 float4, 8 per thread)
        const float* Wc = W + (size_t)chunk * 64 * D_OUT;
        #pragma unroll
        for (int i = 0; i < 8; ++i) {
            int flat = tid + 256 * i;
            int kr = flat >> 5;
            int c4 = flat & 31;
            *(float4*)&Bs[kr][c4 * 4] = *(const float4*)(Wc + kr * D_OUT + c4 * 4);
        }
        __syncthreads();

        #pragma unroll
        for (int k4 = 0; k4 < 16; ++k4) {
            float4 w0 = *(float4*)&Bs[k4 * 4 + 0][tx * 4];
            float4 w1 = *(float4*)&Bs[k4 * 4 + 1][tx * 4];
            float4 w2 = *(float4*)&Bs[k4 * 4 + 2][tx * 4];
            float4 w3 = *(float4*)&Bs[k4 * 4 + 3][tx * 4];
            #pragma unroll
            for (int r = 0; r < 8; ++r) {
                float4 av = *(float4*)&As[ty * 8 + r][k4 * 4];
                acc[r][0] += av.x * w0.x + av.y * w1.x + av.z * w2.x + av.w * w3.x;
                acc[r][1] += av.x * w0.y + av.y * w1.y + av.z * w2.y + av.w * w3.y;
                acc[r][2] += av.x * w0.z + av.y * w1.z + av.z * w2.z + av.w * w3.z;
                acc[r][3] += av.x * w0.w + av.y * w1.w + av.z * w2.w + av.w * w3.w;
            }
        }
        __syncthreads();
    }

    // epilogue: +bias, store bf16 T, accumulate BN1 column sum/sumsq
    float4 bv = *(const float4*)(bias + tx * 4);
    float s0 = 0.f, s1 = 0.f, s2 = 0.f, s3 = 0.f;
    float q0 = 0.f, q1 = 0.f, q2 = 0.f, q3 = 0.f;
    #pragma unroll
    for (int r = 0; r < 8; ++r) {
        int e = e0 + ty * 8 + r;
        float v0 = acc[r][0] + bv.x;
        float v1 = acc[r][1] + bv.y;
        float v2 = acc[r][2] + bv.z;
        float v3 = acc[r][3] + bv.w;
        ushort4 pk;
        pk.x = f32_to_bf16(v0); pk.y = f32_to_bf16(v1);
        pk.z = f32_to_bf16(v2); pk.w = f32_to_bf16(v3);
        *(ushort4*)&T[(size_t)e * D_OUT + tx * 4] = pk;
        s0 += v0; s1 += v1; s2 += v2; s3 += v3;
        q0 += v0 * v0; q1 += v1 * v1; q2 += v2 * v2; q3 += v3 * v3;
    }
    atomicAdd(&stats_s[tx * 4 + 0], s0);
    atomicAdd(&stats_s[tx * 4 + 1], s1);
    atomicAdd(&stats_s[tx * 4 + 2], s2);
    atomicAdd(&stats_s[tx * 4 + 3], s3);
    atomicAdd(&stats_s[128 + tx * 4 + 0], q0);
    atomicAdd(&stats_s[128 + tx * 4 + 1], q1);
    atomicAdd(&stats_s[128 + tx * 4 + 2], q2);
    atomicAdd(&stats_s[128 + tx * 4 + 3], q3);
    __syncthreads();
    atomicAdd(&bn1_stats[tid], stats_s[tid]);
}

// ---- 3: finalize BN1 -> per-column scale/shift ----
__global__ void bn1_finalize(const float* __restrict__ bn1,
                             const float* __restrict__ g1, const float* __restrict__ b1,
                             float* __restrict__ sc) {
    int c = threadIdx.x;
    if (c < 128) {
        float mean = bn1[c] * (1.f / N_EDGES);
        float var  = bn1[128 + c] * (1.f / N_EDGES) - mean * mean;
        float rstd = rsqrtf(var + EPS);
        float s = g1[c] * rstd;
        sc[c] = s;
        sc[128 + c] = b1[c] - mean * s;
    }
}

// ---- 4: BN1 affine + sigmoid*softplus + segment sum (one wave per atom) ----
__global__ __launch_bounds__(64) void msg_kernel(
    const unsigned short* __restrict__ T, const float* __restrict__ sc,
    const int* __restrict__ rs, const int* __restrict__ re,
    float* __restrict__ ns)
{
    int a = blockIdx.x;
    int c = threadIdx.x;
    float scf = sc[c],      shf = sc[128 + c];
    float scc = sc[64 + c], shc = sc[192 + c];
    float acc = 0.f;
    int e1 = re[a];
    for (int e = rs[a]; e < e1; ++e) {
        float tf = bf16_to_f32(T[(size_t)e * D_OUT + c]);
        float tc = bf16_to_f32(T[(size_t)e * D_OUT + 64 + c]);
        float yf = fmaf(tf, scf, shf);
        float yc = fmaf(tc, scc, shc);
        float sig = 1.f / (1.f + __expf(-yf));
        acc += sig * softplus_f(yc);
    }
    ns[a * ELEM + c] = acc;
}

// ---- 5: BN2 column stats ----
__global__ __launch_bounds__(64) void bn2_stats_kernel(
    const float* __restrict__ ns, float* __restrict__ bn2)
{
    int c = threadIdx.x;
    float s = 0.f, ss = 0.f;
    for (int a = blockIdx.x; a < N_ATOMS; a += gridDim.x) {
        float v = ns[a * ELEM + c];
        s += v; ss += v * v;
    }
    atomicAdd(&bn2[c], s);
    atomicAdd(&bn2[64 + c], ss);
}

// ---- 6: BN2 affine + residual + softplus ----
__global__ void final_kernel(const float* __restrict__ atom, const float* __restrict__ ns,
                             const float* __restrict__ bn2,
                             const float* __restrict__ g2, const float* __restrict__ b2,
                             float* __restrict__ out)
{
    int i = blockIdx.x * blockDim.x + threadIdx.x;
    if (i < N_ATOMS * ELEM) {
        int c = i & 63;
        float mean = bn2[c] * (1.f / N_ATOMS);
        float var  = bn2[64 + c] * (1.f / N_ATOMS) - mean * mean;
        float rstd = rsqrtf(var + EPS);
        float s = g2[c] * rstd;
        float o = b2[c] - mean * s;
        float x = atom[i] + fmaf(ns[i], s, o);
        out[i] = softplus_f(x);
    }
}

extern "C" void kernel_launch(void* const* d_in, const int* in_sizes, int n_in,
                              void* d_out, int out_size, void* d_ws, size_t ws_size,
                              hipStream_t stream) {
    const float* atom = (const float*)d_in[0];
    const float* nbrf = (const float*)d_in[1];
    const int*   sidx = (const int*)d_in[2];
    const int*   nidx = (const int*)d_in[3];
    const float* W    = (const float*)d_in[4];
    const float* bias = (const float*)d_in[5];
    const float* g1   = (const float*)d_in[6];
    const float* b1   = (const float*)d_in[7];
    const float* g2   = (const float*)d_in[8];
    const float* b2   = (const float*)d_in[9];
    float* out = (float*)d_out;
    char*  ws  = (char*)d_ws;

    unsigned short* T  = (unsigned short*)(ws + OFF_T);
    float* ns  = (float*)(ws + OFF_NS);
    float* bn1 = (float*)(ws + OFF_BN1);
    float* sc1 = (float*)(ws + OFF_SC1);
    float* bn2 = (float*)(ws + OFF_BN2);
    int*   rs  = (int*)(ws + OFF_RS);
    int*   re  = (int*)(ws + OFF_RE);

    hipLaunchKernelGGL(init_kernel, dim3((N_ATOMS + 255) / 256), dim3(256), 0, stream,
                       rs, re, bn1, bn2);
    hipLaunchKernelGGL(bounds_kernel, dim3((N_EDGES + 255) / 256), dim3(256), 0, stream,
                       sidx, rs, re);
    hipLaunchKernelGGL(gemm_kernel, dim3(N_EDGES / TILE_M), dim3(256), 0, stream,
                       atom, nbrf, sidx, nidx, W, bias, T, bn1);
    hipLaunchKernelGGL(bn1_finalize, dim3(1), dim3(128), 0, stream, bn1, g1, b1, sc1);
    hipLaunchKernelGGL(msg_kernel, dim3(N_ATOMS), dim3(64), 0, stream, T, sc1, rs, re, ns);
    hipLaunchKernelGGL(bn2_stats_kernel, dim3(256), dim3(64), 0, stream, ns, bn2);
    hipLaunchKernelGGL(final_kernel, dim3((N_ATOMS * ELEM + 255) / 256), dim3(256), 0, stream,
                       atom, ns, bn2, g2, b2, out);
}

// Round 2
// 469.777 us; speedup vs baseline: 3.8286x; 3.8286x over previous
//
#include <hip/hip_runtime.h>

typedef unsigned short ushort_t;
typedef __attribute__((ext_vector_type(8))) short short8;
typedef __attribute__((ext_vector_type(4))) float f32x4;

// Problem constants (fixed by the reference)
constexpr int N_ATOMS = 50000;
constexpr int N_EDGES = 800000;
constexpr int ELEM    = 64;
constexpr int D_IN    = 192;   // 2*ELEM + NBR
constexpr int D_OUT   = 128;   // 2*ELEM
constexpr float EPS   = 1e-5f;

constexpr int TILE_M = 64;     // edges per GEMM block

// Workspace layout (bytes), all 16B-aligned
constexpr size_t OFF_T    = 0;                                        // bf16 T[E][128]
constexpr size_t OFF_NS   = OFF_T    + (size_t)N_EDGES * D_OUT * 2;   // f32 ns[N][64]
constexpr size_t OFF_ABF  = OFF_NS   + (size_t)N_ATOMS * ELEM * 4;    // bf16 atom_bf[N][64]
constexpr size_t OFF_WT   = OFF_ABF  + (size_t)N_ATOMS * ELEM * 2;    // bf16 Wt[128][192]
constexpr size_t OFF_BN1  = OFF_WT   + (size_t)D_OUT * D_IN * 2;      // f32 [8][256]
constexpr size_t OFF_SC1  = OFF_BN1  + 8 * 256 * 4;                   // f32 [256]
constexpr size_t OFF_BN2  = OFF_SC1  + 256 * 4;                       // f32 [8][128]
constexpr size_t OFF_SC2  = OFF_BN2  + 8 * 128 * 4;                   // f32 [128]
constexpr size_t OFF_RS   = OFF_SC2  + 128 * 4;                       // int [N]
constexpr size_t OFF_RE   = OFF_RS   + (size_t)N_ATOMS * 4;           // int [N]
// total ~224.5 MB

__device__ __forceinline__ ushort_t f32_to_bf16(float f) {
    unsigned int u = __float_as_uint(f);
    u = (u + 0x7fffu + ((u >> 16) & 1u)) >> 16;   // RNE
    return (ushort_t)u;
}
__device__ __forceinline__ float bf16_to_f32(ushort_t h) {
    return __uint_as_float(((unsigned int)h) << 16);
}
__device__ __forceinline__ float softplus_f(float x) {
    return fmaxf(x, 0.f) + __logf(1.f + __expf(-fabsf(x)));
}

// ---- 0: init segment bounds + stat replicas ----
__global__ void init_kernel(int* __restrict__ rs, int* __restrict__ re,
                            float* __restrict__ bn1r, float* __restrict__ bn2r) {
    int i = blockIdx.x * blockDim.x + threadIdx.x;
    if (i < N_ATOMS) { rs[i] = N_EDGES; re[i] = 0; }
    if (i < 8 * 256) bn1r[i] = 0.f;
    if (i < 8 * 128) bn2r[i] = 0.f;
}

// ---- 1: prep — atom fp32->bf16, W -> Wt bf16 (transposed) ----
__global__ void prep_kernel(const float* __restrict__ atom, const float* __restrict__ W,
                            ushort_t* __restrict__ atom_bf, ushort_t* __restrict__ Wt) {
    int i = blockIdx.x * blockDim.x + threadIdx.x;
    if (i < N_ATOMS * ELEM) atom_bf[i] = f32_to_bf16(atom[i]);
    if (i < D_IN * D_OUT) {
        int n = i & 127, k = i >> 7;                 // coalesced read of W[k][n]
        Wt[n * D_IN + k] = f32_to_bf16(W[k * D_OUT + n]);
    }
}

// ---- 2: per-atom edge ranges via sorted-boundary detection (no atomics) ----
__global__ void bounds_kernel(const int* __restrict__ sidx,
                              int* __restrict__ rs, int* __restrict__ re) {
    int e = blockIdx.x * blockDim.x + threadIdx.x;
    if (e < N_EDGES) {
        int s = sidx[e];
        if (e == 0 || sidx[e - 1] != s) rs[s] = e;
        if (e == N_EDGES - 1 || sidx[e + 1] != s) re[s] = e + 1;
    }
}

// ---- 3: fused gather + bf16 MFMA GEMM + bias, store T bf16 + BN1 stats ----
// Block 256 threads (4 waves). Tile 64 edges x 128 cols, full K=192 in LDS.
__global__ __launch_bounds__(256) void gemm_kernel(
    const ushort_t* __restrict__ atom_bf, const float* __restrict__ nbrf,
    const int* __restrict__ sidx, const int* __restrict__ nidx,
    const ushort_t* __restrict__ Wt, const float* __restrict__ bias,
    ushort_t* __restrict__ T, float* __restrict__ bn1r)
{
    __shared__ char smem[76800];
    ushort_t (*As)[200] = (ushort_t(*)[200])smem;            // [64][200] bf16 (pad 8)
    ushort_t (*Bs)[200] = (ushort_t(*)[200])(smem + 25600);  // [128][200] bf16
    float    (*Cs)[132] = (float(*)[132])smem;               // [64][132] f32 (epilogue reuse)

    const int tid = threadIdx.x;
    const int e0  = blockIdx.x * TILE_M;

    // stage Wt (contiguous 48KB -> padded rows): 12 x 16B per thread
    {
        const uint4* src = (const uint4*)Wt;   // 3072 x 16B
        #pragma unroll
        for (int i = 0; i < 12; ++i) {
            int c = tid + 256 * i;
            int n = c / 24, o = c % 24;        // 24 x 16B per 192-bf16 row
            *(uint4*)&Bs[n][o * 8] = src[c];
        }
    }
    // stage A chunks 0,1: gathered bf16 atom rows (128B each, 8 threads/row)
    #pragma unroll
    for (int ch = 0; ch < 2; ++ch) {
        const int* __restrict__ idx = ch ? nidx : sidx;
        #pragma unroll
        for (int i = 0; i < 2; ++i) {
            int r = (tid >> 3) + 32 * i;
            int h = tid & 7;
            const uint4* src = (const uint4*)(atom_bf + (size_t)idx[e0 + r] * 64);
            *(uint4*)&As[r][ch * 64 + h * 8] = src[h];
        }
    }
    // stage A chunk 2: nbrf fp32 -> bf16 (256B/row, 16 threads/row)
    #pragma unroll
    for (int i = 0; i < 4; ++i) {
        int r  = (tid >> 4) + 16 * i;
        int c4 = tid & 15;
        float4 v = *(const float4*)(nbrf + (size_t)(e0 + r) * 64 + c4 * 4);
        ushort4 pk;
        pk.x = f32_to_bf16(v.x); pk.y = f32_to_bf16(v.y);
        pk.z = f32_to_bf16(v.z); pk.w = f32_to_bf16(v.w);
        *(ushort4*)&As[r][128 + c4 * 4] = pk;
    }
    __syncthreads();

    // MFMA: wave w covers cols [32w, 32w+32); 4 row-tiles x 2 col-tiles of 16x16
    const int wave = tid >> 6;
    const int lane = tid & 63;
    const int m16  = lane & 15;
    const int quad = lane >> 4;

    f32x4 acc[4][2];
    #pragma unroll
    for (int mt = 0; mt < 4; ++mt)
        #pragma unroll
        for (int nt = 0; nt < 2; ++nt)
            acc[mt][nt] = (f32x4){0.f, 0.f, 0.f, 0.f};

    #pragma unroll
    for (int ks = 0; ks < 6; ++ks) {
        int ko = ks * 32 + quad * 8;
        short8 b0 = *(const short8*)&Bs[wave * 32 + m16][ko];
        short8 b1 = *(const short8*)&Bs[wave * 32 + 16 + m16][ko];
        #pragma unroll
        for (int mt = 0; mt < 4; ++mt) {
            short8 a = *(const short8*)&As[mt * 16 + m16][ko];
            acc[mt][0] = __builtin_amdgcn_mfma_f32_16x16x32_bf16(a, b0, acc[mt][0], 0, 0, 0);
            acc[mt][1] = __builtin_amdgcn_mfma_f32_16x16x32_bf16(a, b1, acc[mt][1], 0, 0, 0);
        }
    }
    __syncthreads();   // done reading As/Bs — reuse as Cs

    // acc (+bias) -> Cs.  C/D layout: col = lane&15, row = quad*4 + reg.
    float bias0 = bias[wave * 32 + m16];
    float bias1 = bias[wave * 32 + 16 + m16];
    #pragma unroll
    for (int mt = 0; mt < 4; ++mt) {
        int row = mt * 16 + quad * 4;
        #pragma unroll
        for (int r = 0; r < 4; ++r) {
            Cs[row + r][wave * 32 + m16]      = acc[mt][0][r] + bias0;
            Cs[row + r][wave * 32 + 16 + m16] = acc[mt][1][r] + bias1;
        }
    }
    __syncthreads();

    // coalesced bf16 store of T: 16 threads/row x 16B
    #pragma unroll
    for (int i = 0; i < 4; ++i) {
        int r  = (tid >> 4) + 16 * i;
        int c8 = tid & 15;
        float4 v0 = *(const float4*)&Cs[r][c8 * 8];
        float4 v1 = *(const float4*)&Cs[r][c8 * 8 + 4];
        uint4 u;
        u.x = (unsigned)f32_to_bf16(v0.x) | ((unsigned)f32_to_bf16(v0.y) << 16);
        u.y = (unsigned)f32_to_bf16(v0.z) | ((unsigned)f32_to_bf16(v0.w) << 16);
        u.z = (unsigned)f32_to_bf16(v1.x) | ((unsigned)f32_to_bf16(v1.y) << 16);
        u.w = (unsigned)f32_to_bf16(v1.z) | ((unsigned)f32_to_bf16(v1.w) << 16);
        *(uint4*)&T[(size_t)(e0 + r) * 128 + c8 * 8] = u;
    }

    // BN1 column stats (2 threads/col, 32 rows each) -> replica atomics
    {
        int c = tid & 127;
        int h = tid >> 7;
        float s = 0.f, q = 0.f;
        #pragma unroll
        for (int j = 0; j < 32; ++j) {
            float v = Cs[h * 32 + j][c];
            s += v; q += v * v;
        }
        float* rep = bn1r + (size_t)(blockIdx.x & 7) * 256;
        atomicAdd(&rep[c], s);
        atomicAdd(&rep[128 + c], q);
    }
}

// ---- 4: finalize BN1 -> per-column scale/shift ----
__global__ void bn1_finalize(const float* __restrict__ bn1r,
                             const float* __restrict__ g1, const float* __restrict__ b1,
                             float* __restrict__ sc) {
    int c = threadIdx.x;   // 128
    float s = 0.f, q = 0.f;
    #pragma unroll
    for (int r = 0; r < 8; ++r) { s += bn1r[r * 256 + c]; q += bn1r[r * 256 + 128 + c]; }
    float mean = s * (1.f / N_EDGES);
    float var  = q * (1.f / N_EDGES) - mean * mean;
    float scale = g1[c] * rsqrtf(var + EPS);
    sc[c] = scale;
    sc[128 + c] = b1[c] - mean * scale;
}

// ---- 5: BN1 affine + sigmoid*softplus + segment sum (1 wave/atom, 4/block) ----
__global__ __launch_bounds__(256) void msg_kernel(
    const ushort_t* __restrict__ T, const float* __restrict__ sc,
    const int* __restrict__ rs, const int* __restrict__ re,
    float* __restrict__ ns)
{
    int a = blockIdx.x * 4 + (threadIdx.x >> 6);
    int c = threadIdx.x & 63;
    float scf = sc[c],      shf = sc[128 + c];
    float scc = sc[64 + c], shc = sc[192 + c];
    float acc = 0.f;
    int e = rs[a], e1 = re[a];
    for (; e + 2 <= e1; e += 2) {
        const ushort_t* p0 = T + (size_t)e * 128;
        ushort_t tf0 = p0[c], tc0 = p0[64 + c];
        ushort_t tf1 = p0[128 + c], tc1 = p0[192 + c];
        float yf0 = fmaf(bf16_to_f32(tf0), scf, shf);
        float yc0 = fmaf(bf16_to_f32(tc0), scc, shc);
        float yf1 = fmaf(bf16_to_f32(tf1), scf, shf);
        float yc1 = fmaf(bf16_to_f32(tc1), scc, shc);
        acc += softplus_f(yc0) / (1.f + __expf(-yf0));
        acc += softplus_f(yc1) / (1.f + __expf(-yf1));
    }
    if (e < e1) {
        const ushort_t* p0 = T + (size_t)e * 128;
        float yf = fmaf(bf16_to_f32(p0[c]), scf, shf);
        float yc = fmaf(bf16_to_f32(p0[64 + c]), scc, shc);
        acc += softplus_f(yc) / (1.f + __expf(-yf));
    }
    ns[a * ELEM + c] = acc;
}

// ---- 6: BN2 column stats (replicated atomics) ----
__global__ __launch_bounds__(256) void bn2_stats_kernel(
    const float* __restrict__ ns, float* __restrict__ bn2r)
{
    int c = threadIdx.x & 63;
    float s = 0.f, q = 0.f;
    for (int a = blockIdx.x * 4 + (threadIdx.x >> 6); a < N_ATOMS; a += 4096) {
        float v = ns[a * ELEM + c];
        s += v; q += v * v;
    }
    float* rep = bn2r + (size_t)(blockIdx.x & 7) * 128;
    atomicAdd(&rep[c], s);
    atomicAdd(&rep[64 + c], q);
}

// ---- 7: finalize BN2 ----
__global__ void bn2_finalize(const float* __restrict__ bn2r,
                             const float* __restrict__ g2, const float* __restrict__ b2,
                             float* __restrict__ sc2) {
    int c = threadIdx.x;   // 64
    float s = 0.f, q = 0.f;
    #pragma unroll
    for (int r = 0; r < 8; ++r) { s += bn2r[r * 128 + c]; q += bn2r[r * 128 + 64 + c]; }
    float mean = s * (1.f / N_ATOMS);
    float var  = q * (1.f / N_ATOMS) - mean * mean;
    float scale = g2[c] * rsqrtf(var + EPS);
    sc2[c] = scale;
    sc2[64 + c] = b2[c] - mean * scale;
}

// ---- 8: BN2 affine + residual + softplus ----
__global__ void final_kernel(const float* __restrict__ atom, const float* __restrict__ ns,
                             const float* __restrict__ sc2, float* __restrict__ out)
{
    int i = blockIdx.x * blockDim.x + threadIdx.x;
    if (i < N_ATOMS * ELEM) {
        int c = i & 63;
        float x = atom[i] + fmaf(ns[i], sc2[c], sc2[64 + c]);
        out[i] = softplus_f(x);
    }
}

extern "C" void kernel_launch(void* const* d_in, const int* in_sizes, int n_in,
                              void* d_out, int out_size, void* d_ws, size_t ws_size,
                              hipStream_t stream) {
    const float* atom = (const float*)d_in[0];
    const float* nbrf = (const float*)d_in[1];
    const int*   sidx = (const int*)d_in[2];
    const int*   nidx = (const int*)d_in[3];
    const float* W    = (const float*)d_in[4];
    const float* bias = (const float*)d_in[5];
    const float* g1   = (const float*)d_in[6];
    const float* b1   = (const float*)d_in[7];
    const float* g2   = (const float*)d_in[8];
    const float* b2   = (const float*)d_in[9];
    float* out = (float*)d_out;
    char*  ws  = (char*)d_ws;

    ushort_t* T    = (ushort_t*)(ws + OFF_T);
    float* ns      = (float*)(ws + OFF_NS);
    ushort_t* abf  = (ushort_t*)(ws + OFF_ABF);
    ushort_t* Wt   = (ushort_t*)(ws + OFF_WT);
    float* bn1r    = (float*)(ws + OFF_BN1);
    float* sc1     = (float*)(ws + OFF_SC1);
    float* bn2r    = (float*)(ws + OFF_BN2);
    float* sc2     = (float*)(ws + OFF_SC2);
    int*   rs      = (int*)(ws + OFF_RS);
    int*   re      = (int*)(ws + OFF_RE);

    hipLaunchKernelGGL(init_kernel, dim3((N_ATOMS + 255) / 256), dim3(256), 0, stream,
                       rs, re, bn1r, bn2r);
    hipLaunchKernelGGL(prep_kernel, dim3((N_ATOMS * ELEM + 255) / 256), dim3(256), 0, stream,
                       atom, W, abf, Wt);
    hipLaunchKernelGGL(bounds_kernel, dim3((N_EDGES + 255) / 256), dim3(256), 0, stream,
                       sidx, rs, re);
    hipLaunchKernelGGL(gemm_kernel, dim3(N_EDGES / TILE_M), dim3(256), 0, stream,
                       abf, nbrf, sidx, nidx, Wt, bias, T, bn1r);
    hipLaunchKernelGGL(bn1_finalize, dim3(1), dim3(128), 0, stream, bn1r, g1, b1, sc1);
    hipLaunchKernelGGL(msg_kernel, dim3(N_ATOMS / 4), dim3(256), 0, stream,
                       T, sc1, rs, re, ns);
    hipLaunchKernelGGL(bn2_stats_kernel, dim3(1024), dim3(256), 0, stream, ns, bn2r);
    hipLaunchKernelGGL(bn2_finalize, dim3(1), dim3(64), 0, stream, bn2r, g2, b2, sc2);
    hipLaunchKernelGGL(final_kernel, dim3((N_ATOMS * ELEM + 255) / 256), dim3(256), 0, stream,
                       atom, ns, sc2, out);
}

// Round 3
// 461.022 us; speedup vs baseline: 3.9013x; 1.0190x over previous
//
#include <hip/hip_runtime.h>

typedef unsigned short ushort_t;
typedef __attribute__((ext_vector_type(8))) short short8;
typedef __attribute__((ext_vector_type(4))) float f32x4;

// Problem constants (fixed by the reference)
constexpr int N_ATOMS = 50000;
constexpr int N_EDGES = 800000;
constexpr int ELEM    = 64;
constexpr int D_IN    = 192;   // 2*ELEM + NBR
constexpr int D_OUT   = 128;   // 2*ELEM
constexpr float EPS   = 1e-5f;

constexpr int TILE_M = 64;     // edges per GEMM block
constexpr int NREP   = 16;     // stat-accumulator replicas

// Workspace layout (bytes), 16B-aligned. Total ~19.3 MB (no T!).
constexpr size_t OFF_NS   = 0;                                        // f32 ns[N][64]
constexpr size_t OFF_ABF  = OFF_NS   + (size_t)N_ATOMS * ELEM * 4;    // bf16 atom_bf[N][64]
constexpr size_t OFF_WT   = OFF_ABF  + (size_t)N_ATOMS * ELEM * 2;    // bf16 Wt[128][192]
constexpr size_t OFF_BN1  = OFF_WT   + (size_t)D_OUT * D_IN * 2;      // f32 [NREP][256]
constexpr size_t OFF_SC1  = OFF_BN1  + NREP * 256 * 4;                // f32 [256]
constexpr size_t OFF_BN2  = OFF_SC1  + 256 * 4;                       // f32 [NREP][128]
constexpr size_t OFF_SC2  = OFF_BN2  + NREP * 128 * 4;                // f32 [128]

__device__ __forceinline__ ushort_t f32_to_bf16(float f) {
    unsigned int u = __float_as_uint(f);
    u = (u + 0x7fffu + ((u >> 16) & 1u)) >> 16;   // RNE
    return (ushort_t)u;
}
__device__ __forceinline__ float bf16_to_f32(ushort_t h) {
    return __uint_as_float(((unsigned int)h) << 16);
}
__device__ __forceinline__ float softplus_f(float x) {
    return fmaxf(x, 0.f) + __logf(1.f + __expf(-fabsf(x)));
}

// ---- 0: prep + init: atom->bf16, W->Wt (bf16 transposed), zero ns + replicas ----
__global__ void prep_init_kernel(const float* __restrict__ atom, const float* __restrict__ W,
                                 ushort_t* __restrict__ abf, ushort_t* __restrict__ Wt,
                                 float* __restrict__ ns,
                                 float* __restrict__ bn1r, float* __restrict__ bn2r) {
    int i = blockIdx.x * blockDim.x + threadIdx.x;
    if (i < N_ATOMS * ELEM) { abf[i] = f32_to_bf16(atom[i]); ns[i] = 0.f; }
    if (i < D_IN * D_OUT) {
        int k = i >> 7, n = i & 127;                 // coalesced read of W[k][n]
        Wt[n * D_IN + k] = f32_to_bf16(W[i]);
    }
    if (i < NREP * 256) bn1r[i] = 0.f;
    if (i < NREP * 128) bn2r[i] = 0.f;
}

// ---- shared GEMM staging (known-good from round 2) ----
__device__ __forceinline__ void stage_A(ushort_t (*As)[200],
                                        const ushort_t* __restrict__ abf,
                                        const float* __restrict__ nbrf,
                                        const int* __restrict__ sidx,
                                        const int* __restrict__ nidx,
                                        int e0, int tid) {
    #pragma unroll
    for (int ch = 0; ch < 2; ++ch) {
        const int* __restrict__ idx = ch ? nidx : sidx;
        #pragma unroll
        for (int i = 0; i < 2; ++i) {
            int r = (tid >> 3) + 32 * i;
            int h = tid & 7;
            const uint4* src = (const uint4*)(abf + (size_t)idx[e0 + r] * 64);
            *(uint4*)&As[r][ch * 64 + h * 8] = src[h];
        }
    }
    #pragma unroll
    for (int i = 0; i < 4; ++i) {
        int r  = (tid >> 4) + 16 * i;
        int c4 = tid & 15;
        float4 v = *(const float4*)(nbrf + (size_t)(e0 + r) * 64 + c4 * 4);
        ushort4 pk;
        pk.x = f32_to_bf16(v.x); pk.y = f32_to_bf16(v.y);
        pk.z = f32_to_bf16(v.z); pk.w = f32_to_bf16(v.w);
        *(ushort4*)&As[r][128 + c4 * 4] = pk;
    }
}

// ---- 1: stats pass — gather+MFMA+bias, column sum/sumsq straight from regs ----
__global__ __launch_bounds__(256) void stats_kernel(
    const ushort_t* __restrict__ abf, const float* __restrict__ nbrf,
    const int* __restrict__ sidx, const int* __restrict__ nidx,
    const ushort_t* __restrict__ Wt, const float* __restrict__ bias,
    float* __restrict__ bn1r)
{
    __shared__ __align__(16) ushort_t As[64][200];   // 25.6 KB
    const int tid = threadIdx.x;
    const int e0  = blockIdx.x * TILE_M;

    stage_A(As, abf, nbrf, sidx, nidx, e0, tid);

    const int wave = tid >> 6, lane = tid & 63;
    const int m16 = lane & 15, quad = lane >> 4;

    // B fragments from global (48 KB Wt is L2-resident): cols wave*32+nt*16+m16
    short8 bfrag[2][6];
    #pragma unroll
    for (int nt = 0; nt < 2; ++nt) {
        const ushort_t* bp = Wt + (size_t)(wave * 32 + nt * 16 + m16) * D_IN + quad * 8;
        #pragma unroll
        for (int ks = 0; ks < 6; ++ks) bfrag[nt][ks] = *(const short8*)(bp + ks * 32);
    }
    __syncthreads();

    f32x4 acc[4][2];
    #pragma unroll
    for (int mt = 0; mt < 4; ++mt)
        #pragma unroll
        for (int nt = 0; nt < 2; ++nt) acc[mt][nt] = (f32x4){0.f, 0.f, 0.f, 0.f};

    #pragma unroll
    for (int ks = 0; ks < 6; ++ks) {
        int ko = ks * 32 + quad * 8;
        #pragma unroll
        for (int mt = 0; mt < 4; ++mt) {
            short8 a = *(const short8*)&As[mt * 16 + m16][ko];
            acc[mt][0] = __builtin_amdgcn_mfma_f32_16x16x32_bf16(a, bfrag[0][ks], acc[mt][0], 0, 0, 0);
            acc[mt][1] = __builtin_amdgcn_mfma_f32_16x16x32_bf16(a, bfrag[1][ks], acc[mt][1], 0, 0, 0);
        }
    }

    // per-lane partial col stats over its 16 rows, butterfly over quad, atomics
    float* rep = bn1r + (size_t)(blockIdx.x & (NREP - 1)) * 256;
    #pragma unroll
    for (int nt = 0; nt < 2; ++nt) {
        int c = wave * 32 + nt * 16 + m16;
        float b = bias[c];
        float s = 0.f, q = 0.f;
        #pragma unroll
        for (int mt = 0; mt < 4; ++mt)
            #pragma unroll
            for (int r = 0; r < 4; ++r) {
                float v = acc[mt][nt][r] + b;
                s += v; q += v * v;
            }
        s += __shfl_xor(s, 16); s += __shfl_xor(s, 32);
        q += __shfl_xor(q, 16); q += __shfl_xor(q, 32);
        if (quad == 0) {
            atomicAdd(&rep[c], s);
            atomicAdd(&rep[128 + c], q);
        }
    }
}

// ---- 2: finalize BN1 -> per-column scale/shift ----
__global__ void bn1_finalize(const float* __restrict__ bn1r,
                             const float* __restrict__ g1, const float* __restrict__ b1,
                             float* __restrict__ sc) {
    int c = threadIdx.x;   // 128
    float s = 0.f, q = 0.f;
    #pragma unroll
    for (int r = 0; r < NREP; ++r) { s += bn1r[r * 256 + c]; q += bn1r[r * 256 + 128 + c]; }
    float mean = s * (1.f / N_EDGES);
    float var  = q * (1.f / N_EDGES) - mean * mean;
    float scale = g1[c] * rsqrtf(var + EPS);
    sc[c] = scale;
    sc[128 + c] = b1[c] - mean * scale;
}

// ---- 3: msg pass — recompute GEMM, BN1 affine + gate in regs, segment-sum ----
// Wave w holds filter col 16w+m16 (nt=0) and core col 64+16w+m16 (nt=1):
// the gate sigmoid(f)*softplus(c) pairs up inside one lane, no exchange.
__global__ __launch_bounds__(256) void msg_kernel(
    const ushort_t* __restrict__ abf, const float* __restrict__ nbrf,
    const int* __restrict__ sidx, const int* __restrict__ nidx,
    const ushort_t* __restrict__ Wt, const float* __restrict__ bias,
    const float* __restrict__ sc, float* __restrict__ ns)
{
    __shared__ __align__(16) char smem[25600];
    ushort_t (*As)[200] = (ushort_t(*)[200])smem;     // 25.6 KB (GEMM phase)
    float    (*Ms)[68]  = (float(*)[68])smem;         // 17.4 KB (msg phase, aliases As)
    __shared__ int ss[64];

    const int tid = threadIdx.x;
    const int e0  = blockIdx.x * TILE_M;

    stage_A(As, abf, nbrf, sidx, nidx, e0, tid);
    if (tid < 64) ss[tid] = sidx[e0 + tid];

    const int wave = tid >> 6, lane = tid & 63;
    const int m16 = lane & 15, quad = lane >> 4;
    const int cf = wave * 16 + m16;        // filter col 0..63
    const int cc = 64 + cf;                // core col 64..127

    short8 bfrag[2][6];
    {
        const ushort_t* bp0 = Wt + (size_t)cf * D_IN + quad * 8;
        const ushort_t* bp1 = Wt + (size_t)cc * D_IN + quad * 8;
        #pragma unroll
        for (int ks = 0; ks < 6; ++ks) {
            bfrag[0][ks] = *(const short8*)(bp0 + ks * 32);
            bfrag[1][ks] = *(const short8*)(bp1 + ks * 32);
        }
    }
    __syncthreads();

    f32x4 acc[4][2];
    #pragma unroll
    for (int mt = 0; mt < 4; ++mt)
        #pragma unroll
        for (int nt = 0; nt < 2; ++nt) acc[mt][nt] = (f32x4){0.f, 0.f, 0.f, 0.f};

    #pragma unroll
    for (int ks = 0; ks < 6; ++ks) {
        int ko = ks * 32 + quad * 8;
        #pragma unroll
        for (int mt = 0; mt < 4; ++mt) {
            short8 a = *(const short8*)&As[mt * 16 + m16][ko];
            acc[mt][0] = __builtin_amdgcn_mfma_f32_16x16x32_bf16(a, bfrag[0][ks], acc[mt][0], 0, 0, 0);
            acc[mt][1] = __builtin_amdgcn_mfma_f32_16x16x32_bf16(a, bfrag[1][ks], acc[mt][1], 0, 0, 0);
        }
    }
    __syncthreads();   // done reading As — alias as Ms now

    // gate in registers, write msg tile to LDS
    {
        float bf_ = bias[cf], bc_ = bias[cc];
        float scf = sc[cf], shf = sc[128 + cf];
        float scc = sc[cc], shc = sc[128 + cc];
        #pragma unroll
        for (int mt = 0; mt < 4; ++mt) {
            int row = mt * 16 + quad * 4;
            #pragma unroll
            for (int r = 0; r < 4; ++r) {
                float yf = fmaf(acc[mt][0][r] + bf_, scf, shf);
                float yc = fmaf(acc[mt][1][r] + bc_, scc, shc);
                Ms[row + r][cf] = softplus_f(yc) / (1.f + __expf(-yf));
            }
        }
    }
    __syncthreads();

    // run-detection segment sum (sidx sorted): thread (v,c) scans 16 rows of col c
    {
        int v = tid >> 6, c = tid & 63;
        int base = v * 16;
        int cur = ss[base];
        float a = 0.f;
        #pragma unroll
        for (int r = 0; r < 16; ++r) {
            int s = ss[base + r];
            if (s != cur) { atomicAdd(&ns[(size_t)cur * 64 + c], a); cur = s; a = 0.f; }
            a += Ms[base + r][c];
        }
        atomicAdd(&ns[(size_t)cur * 64 + c], a);
    }
}

// ---- 4: BN2 column stats (replicated atomics) ----
__global__ __launch_bounds__(256) void bn2_stats_kernel(
    const float* __restrict__ ns, float* __restrict__ bn2r)
{
    int c = threadIdx.x & 63;
    float s = 0.f, q = 0.f;
    for (int a = blockIdx.x * 4 + (threadIdx.x >> 6); a < N_ATOMS; a += 4096) {
        float v = ns[a * ELEM + c];
        s += v; q += v * v;
    }
    float* rep = bn2r + (size_t)(blockIdx.x & (NREP - 1)) * 128;
    atomicAdd(&rep[c], s);
    atomicAdd(&rep[64 + c], q);
}

// ---- 5: finalize BN2 ----
__global__ void bn2_finalize(const float* __restrict__ bn2r,
                             const float* __restrict__ g2, const float* __restrict__ b2,
                             float* __restrict__ sc2) {
    int c = threadIdx.x;   // 64
    float s = 0.f, q = 0.f;
    #pragma unroll
    for (int r = 0; r < NREP; ++r) { s += bn2r[r * 128 + c]; q += bn2r[r * 128 + 64 + c]; }
    float mean = s * (1.f / N_ATOMS);
    float var  = q * (1.f / N_ATOMS) - mean * mean;
    float scale = g2[c] * rsqrtf(var + EPS);
    sc2[c] = scale;
    sc2[64 + c] = b2[c] - mean * scale;
}

// ---- 6: BN2 affine + residual + softplus ----
__global__ void final_kernel(const float* __restrict__ atom, const float* __restrict__ ns,
                             const float* __restrict__ sc2, float* __restrict__ out)
{
    int i = blockIdx.x * blockDim.x + threadIdx.x;
    if (i < N_ATOMS * ELEM) {
        int c = i & 63;
        float x = atom[i] + fmaf(ns[i], sc2[c], sc2[64 + c]);
        out[i] = softplus_f(x);
    }
}

extern "C" void kernel_launch(void* const* d_in, const int* in_sizes, int n_in,
                              void* d_out, int out_size, void* d_ws, size_t ws_size,
                              hipStream_t stream) {
    const float* atom = (const float*)d_in[0];
    const float* nbrf = (const float*)d_in[1];
    const int*   sidx = (const int*)d_in[2];
    const int*   nidx = (const int*)d_in[3];
    const float* W    = (const float*)d_in[4];
    const float* bias = (const float*)d_in[5];
    const float* g1   = (const float*)d_in[6];
    const float* b1   = (const float*)d_in[7];
    const float* g2   = (const float*)d_in[8];
    const float* b2   = (const float*)d_in[9];
    float* out = (float*)d_out;
    char*  ws  = (char*)d_ws;

    float*    ns   = (float*)(ws + OFF_NS);
    ushort_t* abf  = (ushort_t*)(ws + OFF_ABF);
    ushort_t* Wt   = (ushort_t*)(ws + OFF_WT);
    float*    bn1r = (float*)(ws + OFF_BN1);
    float*    sc1  = (float*)(ws + OFF_SC1);
    float*    bn2r = (float*)(ws + OFF_BN2);
    float*    sc2  = (float*)(ws + OFF_SC2);

    hipLaunchKernelGGL(prep_init_kernel, dim3((N_ATOMS * ELEM + 255) / 256), dim3(256), 0, stream,
                       atom, W, abf, Wt, ns, bn1r, bn2r);
    hipLaunchKernelGGL(stats_kernel, dim3(N_EDGES / TILE_M), dim3(256), 0, stream,
                       abf, nbrf, sidx, nidx, Wt, bias, bn1r);
    hipLaunchKernelGGL(bn1_finalize, dim3(1), dim3(128), 0, stream, bn1r, g1, b1, sc1);
    hipLaunchKernelGGL(msg_kernel, dim3(N_EDGES / TILE_M), dim3(256), 0, stream,
                       abf, nbrf, sidx, nidx, Wt, bias, sc1, ns);
    hipLaunchKernelGGL(bn2_stats_kernel, dim3(1024), dim3(256), 0, stream, ns, bn2r);
    hipLaunchKernelGGL(bn2_finalize, dim3(1), dim3(64), 0, stream, bn2r, g2, b2, sc2);
    hipLaunchKernelGGL(final_kernel, dim3((N_ATOMS * ELEM + 255) / 256), dim3(256), 0, stream,
                       atom, ns, sc2, out);
}